// Round 13
// baseline (135.570 us; speedup 1.0000x reference)
//
#include <hip/hip_runtime.h>

#define NBATCH 256
#define NCH 30

typedef __attribute__((ext_vector_type(4))) float f32x4;

__device__ __forceinline__ float fast_sqrt(float x) {
    float r;
    asm("v_sqrt_f32 %0, %1" : "=v"(r) : "v"(x));
    return r;
}

// Compiler-proof loads: volatile asm cannot be reordered/sunk/deleted.
__device__ __forceinline__ f32x4 gld128(const float* p) {
    f32x4 r;
    asm volatile("global_load_dwordx4 %0, %1, off" : "=v"(r) : "v"(p));
    return r;
}
__device__ __forceinline__ float gld32(const float* p) {
    float r;
    asm volatile("global_load_dword %0, %1, off" : "=v"(r) : "v"(p));
    return r;
}

// One float4 worth of loss. (sqrt(p)-sqrt(t))^2 == p + t - 2*sqrt(p*t).
// obj selection: only phase c0==28 straddles two cells; there k=0,1 are the
// lo cell and k=2,3 the hi cell; all other phases have chi==clo.
__device__ __forceinline__ float quad_term(
    f32x4 pv, f32x4 tv, float clo, float chi,
    const float WA[4], const float WB[4], const bool SQ[4])
{
    float obj_lo = (clo == 1.0f) ? 1.0f : 0.0f;
    float obj_hi = (chi == 1.0f) ? 1.0f : 0.0f;
    float acc = 0.0f;
    #pragma unroll
    for (int k = 0; k < 4; ++k) {
        float p = pv[k], t = tv[k];
        float dns = p - t;
        float vns = dns * dns;
        float vsq = (p + t) - 2.0f * fast_sqrt(p * t);
        float val = SQ[k] ? vsq : vns;
        float ob  = (k < 2) ? obj_lo : obj_hi;
        float w   = fmaf(ob, WA[k], WB[k]);
        acc = fmaf(w, val, acc);
    }
    return acc;
}

// Persistent pipelined streaming kernel (R12 memory loop) + fenced
// last-block-done finish: partials -> d_ws, __threadfence + counter atomic,
// last block sums partials in fixed index order (deterministic) -> out.
// Single kernel: no finish-kernel launch gap on the critical path.
// w(c, obj) = obj*WA + WB:  c<4 -> (5,0);  c==4 -> (0.5,0.5);  c>=5 -> (1,0).
template <bool USE_WS>
__global__ __launch_bounds__(256, 8) void yolo_loss_main_kernel(
    const float* __restrict__ pred,
    const float* __restrict__ targ,
    float* __restrict__ partial,    // USE_WS: per-block partials (d_ws+64)
    unsigned int* __restrict__ counter, // USE_WS: done-counter (d_ws+0)
    float* __restrict__ out,
    int n4)
{
    const int T   = gridDim.x * blockDim.x;     // 2940*256 = 752,640
    const int tid = blockIdx.x * blockDim.x + threadIdx.x;

    const int e0    = tid * 4;
    const int c0    = e0 % NCH;                 // even; iteration-invariant
    const int cell0 = e0 / NCH;
    const int Flo0  = cell0 * NCH + 4;          // lo-cell conf flat index
    const int hioff = (c0 == 28) ? NCH : 0;     // straddle -> next cell's conf

    float WA[4], WB[4];
    bool  SQ[4];
    #pragma unroll
    for (int k = 0; k < 4; ++k) {
        int c = c0 + k; if (c >= NCH) c -= NCH;
        SQ[k] = (c == 2 || c == 3);
        if (c < 4)       { WA[k] = 5.0f; WB[k] = 0.0f; }
        else if (c == 4) { WA[k] = 0.5f; WB[k] = 0.5f; }
        else             { WA[k] = 1.0f; WB[k] = 0.0f; }
    }

    float acc = 0.0f;

    if (n4 == 8 * T) {
        // ---------- fast path (shipped shape): 8 iters, depth-2 pipeline ----------
        const int S = 4 * T;                    // element stride per iteration
        const float* pp = pred + e0;
        const float* tp = targ + e0;
        const float* cl = targ + Flo0;
        const float* ch = targ + Flo0 + hioff;

        f32x4 pvX = gld128(pp);
        f32x4 tvX = gld128(tp);
        float cloX = gld32(cl);
        float chiX = gld32(ch);
        f32x4 pvY, tvY;
        float cloY, chiY;

        #define STEP(CUR, NXT)                                              \
            pp += S; tp += S; cl += S; ch += S;                             \
            pv##NXT  = gld128(pp);                                          \
            tv##NXT  = gld128(tp);                                          \
            clo##NXT = gld32(cl);                                           \
            chi##NXT = gld32(ch);                                           \
            asm volatile("s_waitcnt vmcnt(4)" ::: "memory");                \
            __builtin_amdgcn_sched_barrier(0);                              \
            acc += quad_term(pv##CUR, tv##CUR, clo##CUR, chi##CUR, WA, WB, SQ);

        STEP(X, Y)
        STEP(Y, X)
        STEP(X, Y)
        STEP(Y, X)
        STEP(X, Y)
        STEP(Y, X)
        STEP(X, Y)
        #undef STEP

        asm volatile("s_waitcnt vmcnt(0)" ::: "memory");
        __builtin_amdgcn_sched_barrier(0);
        acc += quad_term(pvY, tvY, cloY, chiY, WA, WB, SQ);
    } else {
        // ---------- generic fallback (any n4; grid always mult of 15) ----------
        const int S = 4 * T;
        const float4* p4 = reinterpret_cast<const float4*>(pred);
        const float4* t4 = reinterpret_cast<const float4*>(targ);
        int m = 0;
        for (int i = tid; i < n4; i += T, ++m) {
            float4 pv = p4[i];
            float4 tv = t4[i];
            f32x4 pvv; pvv[0]=pv.x; pvv[1]=pv.y; pvv[2]=pv.z; pvv[3]=pv.w;
            f32x4 tvv; tvv[0]=tv.x; tvv[1]=tv.y; tvv[2]=tv.z; tvv[3]=tv.w;
            float clo = targ[Flo0 + m * S];
            float chi = targ[Flo0 + hioff + m * S];
            acc += quad_term(pvv, tvv, clo, chi, WA, WB, SQ);
        }
    }

    // wave64 shuffle reduction -> block LDS
    #pragma unroll
    for (int off = 32; off > 0; off >>= 1)
        acc += __shfl_down(acc, off, 64);

    __shared__ float lds[4];
    __shared__ bool  last;
    int lane = threadIdx.x & 63;
    int wid  = threadIdx.x >> 6;
    if (lane == 0) lds[wid] = acc;
    __syncthreads();

    if (!USE_WS) {
        if (threadIdx.x == 0) {
            float s = lds[0] + lds[1] + lds[2] + lds[3];
            atomicAdd(out, s * (1.0f / (float)NBATCH));
        }
        return;
    }

    if (threadIdx.x == 0) {
        float s = lds[0] + lds[1] + lds[2] + lds[3];
        partial[blockIdx.x] = s;
        __threadfence();                        // release: partial visible device-wide
        last = (atomicAdd(counter, 1u) == gridDim.x - 1);
    }
    __syncthreads();

    if (last) {
        __threadfence();                        // acquire: see all partials
        const int nb = gridDim.x;
        float a = 0.0f;
        for (int i = threadIdx.x; i < nb; i += 256) a += partial[i];
        #pragma unroll
        for (int off = 32; off > 0; off >>= 1)
            a += __shfl_down(a, off, 64);
        if (lane == 0) lds[wid] = a;            // prior reads done at the barrier
        __syncthreads();
        if (threadIdx.x == 0)
            out[0] = (lds[0] + lds[1] + lds[2] + lds[3]) * (1.0f / (float)NBATCH);
    }
}

extern "C" void kernel_launch(void* const* d_in, const int* in_sizes, int n_in,
                              void* d_out, int out_size, void* d_ws, size_t ws_size,
                              hipStream_t stream)
{
    const float* pred = (const float*)d_in[0];
    const float* targ = (const float*)d_in[1];
    float* out = (float*)d_out;

    int n  = in_sizes[0];   // 24,084,480
    int n4 = n / 4;         // 6,021,120

    // 2940 ≡ 0 (mod 15): iteration-invariant channel phase; 8 float4/thread exactly.
    int blocks = 2940;

    // d_ws layout: [0..63] counter cache line, [64 ..) per-block partials
    if (ws_size >= 64 + (size_t)blocks * sizeof(float)) {
        unsigned int* counter = (unsigned int*)d_ws;
        float* partial = (float*)((char*)d_ws + 64);
        hipMemsetAsync(counter, 0, sizeof(unsigned int), stream);  // re-arm each call
        yolo_loss_main_kernel<true><<<blocks, 256, 0, stream>>>(
            pred, targ, partial, counter, out, n4);
    } else {
        hipMemsetAsync(out, 0, sizeof(float), stream);
        yolo_loss_main_kernel<false><<<blocks, 256, 0, stream>>>(
            pred, targ, nullptr, nullptr, out, n4);
    }
}

// Round 15
// 38.208 us; speedup vs baseline: 3.5482x; 3.5482x over previous
//
#include <hip/hip_runtime.h>

#define NBATCH 256
#define NCH 30

typedef __attribute__((ext_vector_type(4))) float f32x4;

__device__ __forceinline__ float fast_sqrt(float x) {
    float r;
    asm("v_sqrt_f32 %0, %1" : "=v"(r) : "v"(x));
    return r;
}

// Compiler-proof loads: volatile asm cannot be reordered/sunk/deleted,
// and keeps the pipeline registers genuinely live.
__device__ __forceinline__ f32x4 gld128(const float* p) {
    f32x4 r;
    asm volatile("global_load_dwordx4 %0, %1, off" : "=v"(r) : "v"(p));
    return r;
}
__device__ __forceinline__ float gld32(const float* p) {
    float r;
    asm volatile("global_load_dword %0, %1, off" : "=v"(r) : "v"(p));
    return r;
}

// One float4 worth of loss. (sqrt(p)-sqrt(t))^2 == p + t - 2*sqrt(p*t).
// obj selection: only phase c0==28 straddles two cells; there k=0,1 are the
// lo cell and k=2,3 the hi cell; all other phases have chi==clo.
__device__ __forceinline__ float quad_term(
    f32x4 pv, f32x4 tv, float clo, float chi,
    const float WA[4], const float WB[4], const bool SQ[4])
{
    float obj_lo = (clo == 1.0f) ? 1.0f : 0.0f;
    float obj_hi = (chi == 1.0f) ? 1.0f : 0.0f;
    float acc = 0.0f;
    #pragma unroll
    for (int k = 0; k < 4; ++k) {
        float p = pv[k], t = tv[k];
        float dns = p - t;
        float vns = dns * dns;
        float vsq = (p + t) - 2.0f * fast_sqrt(p * t);
        float val = SQ[k] ? vsq : vns;
        float ob  = (k < 2) ? obj_lo : obj_hi;
        float w   = fmaf(ob, WA[k], WB[k]);
        acc = fmaf(w, val, acc);
    }
    return acc;
}

// Persistent pipelined streaming kernel (R12 — best verified, 38.4 µs).
// Grid ≡ 0 (mod 15) -> 4T ≡ 0 (mod 30): channel phase c0 is iteration-
// invariant. 8 iterations/thread, software pipeline depth 2: iter i+1's 4
// unconditional asm loads are issued before a counted s_waitcnt vmcnt(4)
// releases iter i's consume — 8 VMEM in flight per wave continuously.
// All VMEM in the fast path is unconditional asm (hand-counted vmcnt is only
// valid under that condition — R14's conditional-load variant NaN'd).
// w(c, obj) = obj*WA + WB:  c<4 -> (5,0);  c==4 -> (0.5,0.5);  c>=5 -> (1,0).
template <bool USE_WS>
__global__ __launch_bounds__(256, 8) void yolo_loss_main_kernel(
    const float* __restrict__ pred,
    const float* __restrict__ targ,
    float* __restrict__ out,        // USE_WS ? per-block partials : atomic target
    int n4)
{
    const int T   = gridDim.x * blockDim.x;     // 2940*256 = 752,640
    const int tid = blockIdx.x * blockDim.x + threadIdx.x;

    const int e0    = tid * 4;
    const int c0    = e0 % NCH;                 // even; iteration-invariant
    const int cell0 = e0 / NCH;
    const int Flo0  = cell0 * NCH + 4;          // lo-cell conf flat index
    const int hioff = (c0 == 28) ? NCH : 0;     // straddle -> next cell's conf

    float WA[4], WB[4];
    bool  SQ[4];
    #pragma unroll
    for (int k = 0; k < 4; ++k) {
        int c = c0 + k; if (c >= NCH) c -= NCH;
        SQ[k] = (c == 2 || c == 3);
        if (c < 4)       { WA[k] = 5.0f; WB[k] = 0.0f; }
        else if (c == 4) { WA[k] = 0.5f; WB[k] = 0.5f; }
        else             { WA[k] = 1.0f; WB[k] = 0.0f; }
    }

    float acc = 0.0f;

    if (n4 == 8 * T) {
        // ---------- fast path (shipped shape): 8 iters, depth-2 pipeline ----------
        const int S = 4 * T;                    // element stride per iteration
        const float* pp = pred + e0;
        const float* tp = targ + e0;
        const float* cl = targ + Flo0;
        const float* ch = targ + Flo0 + hioff;

        f32x4 pvX = gld128(pp);
        f32x4 tvX = gld128(tp);
        float cloX = gld32(cl);
        float chiX = gld32(ch);
        f32x4 pvY, tvY;
        float cloY, chiY;

        #define STEP(CUR, NXT)                                              \
            pp += S; tp += S; cl += S; ch += S;                             \
            pv##NXT  = gld128(pp);                                          \
            tv##NXT  = gld128(tp);                                          \
            clo##NXT = gld32(cl);                                           \
            chi##NXT = gld32(ch);                                           \
            asm volatile("s_waitcnt vmcnt(4)" ::: "memory");                \
            __builtin_amdgcn_sched_barrier(0);                              \
            acc += quad_term(pv##CUR, tv##CUR, clo##CUR, chi##CUR, WA, WB, SQ);

        STEP(X, Y)
        STEP(Y, X)
        STEP(X, Y)
        STEP(Y, X)
        STEP(X, Y)
        STEP(Y, X)
        STEP(X, Y)
        #undef STEP

        asm volatile("s_waitcnt vmcnt(0)" ::: "memory");
        __builtin_amdgcn_sched_barrier(0);
        acc += quad_term(pvY, tvY, cloY, chiY, WA, WB, SQ);
    } else {
        // ---------- generic fallback (any n4; grid always mult of 15) ----------
        const int S = 4 * T;
        const float4* p4 = reinterpret_cast<const float4*>(pred);
        const float4* t4 = reinterpret_cast<const float4*>(targ);
        int m = 0;
        for (int i = tid; i < n4; i += T, ++m) {
            float4 pv = p4[i];
            float4 tv = t4[i];
            f32x4 pvv; pvv[0]=pv.x; pvv[1]=pv.y; pvv[2]=pv.z; pvv[3]=pv.w;
            f32x4 tvv; tvv[0]=tv.x; tvv[1]=tv.y; tvv[2]=tv.z; tvv[3]=tv.w;
            float clo = targ[Flo0 + m * S];
            float chi = targ[Flo0 + hioff + m * S];
            acc += quad_term(pvv, tvv, clo, chi, WA, WB, SQ);
        }
    }

    // wave64 shuffle reduction -> block LDS -> partial store / atomic
    #pragma unroll
    for (int off = 32; off > 0; off >>= 1)
        acc += __shfl_down(acc, off, 64);

    __shared__ float lds[4];
    int lane = threadIdx.x & 63;
    int wid  = threadIdx.x >> 6;
    if (lane == 0) lds[wid] = acc;
    __syncthreads();
    if (threadIdx.x == 0) {
        float s = lds[0] + lds[1] + lds[2] + lds[3];
        if (USE_WS) out[blockIdx.x] = s;
        else        atomicAdd(out, s * (1.0f / (float)NBATCH));
    }
}

// Sum nblocks partials -> out[0], fold the 1/NBATCH.
__global__ __launch_bounds__(256) void yolo_loss_finish_kernel(
    const float* __restrict__ partial, float* __restrict__ out, int n)
{
    float acc = 0.0f;
    for (int i = threadIdx.x; i < n; i += 256) acc += partial[i];
    #pragma unroll
    for (int off = 32; off > 0; off >>= 1)
        acc += __shfl_down(acc, off, 64);
    __shared__ float lds[4];
    int lane = threadIdx.x & 63, wid = threadIdx.x >> 6;
    if (lane == 0) lds[wid] = acc;
    __syncthreads();
    if (threadIdx.x == 0)
        out[0] = (lds[0] + lds[1] + lds[2] + lds[3]) * (1.0f / (float)NBATCH);
}

extern "C" void kernel_launch(void* const* d_in, const int* in_sizes, int n_in,
                              void* d_out, int out_size, void* d_ws, size_t ws_size,
                              hipStream_t stream)
{
    const float* pred = (const float*)d_in[0];
    const float* targ = (const float*)d_in[1];
    float* out = (float*)d_out;

    int n  = in_sizes[0];   // 24,084,480
    int n4 = n / 4;         // 6,021,120

    // 2940 ≡ 0 (mod 15): iteration-invariant channel phase; 8 float4/thread exactly.
    int blocks = 2940;

    if (ws_size >= (size_t)blocks * sizeof(float)) {
        float* partial = (float*)d_ws;
        yolo_loss_main_kernel<true><<<blocks, 256, 0, stream>>>(pred, targ, partial, n4);
        yolo_loss_finish_kernel<<<1, 256, 0, stream>>>(partial, out, blocks);
    } else {
        hipMemsetAsync(out, 0, sizeof(float), stream);
        yolo_loss_main_kernel<false><<<blocks, 256, 0, stream>>>(pred, targ, out, n4);
    }
}